// Round 1
// baseline (4391.224 us; speedup 1.0000x reference)
//
#include <hip/hip_runtime.h>

#define NODES   50000
#define EDGES   800000
#define GRAPHS  500
#define HID     128
#define OUTC    10
#define NLAYERS 3

// ---------------------------------------------------------------------------
// Scatter-add: agg[dst[e]] += x[src[e]]   (128 channels, float4 per thread)
// ---------------------------------------------------------------------------
__global__ __launch_bounds__(256) void scatter_kernel(
    const float* __restrict__ x,
    const int*   __restrict__ src,
    const int*   __restrict__ dst,
    float*       __restrict__ agg)
{
    int idx = blockIdx.x * 256 + threadIdx.x;
    int e = idx >> 5;                 // 32 threads per edge
    if (e >= EDGES) return;
    int c = (idx & 31) << 2;          // channel group of 4
    int s = src[e];
    int d = dst[e];
    const float4 v = *reinterpret_cast<const float4*>(x + (size_t)s * HID + c);
    float* p = agg + (size_t)d * HID + c;
    unsafeAtomicAdd(p + 0, v.x);
    unsafeAtomicAdd(p + 1, v.y);
    unsafeAtomicAdd(p + 2, v.z);
    unsafeAtomicAdd(p + 3, v.w);
}

// ---------------------------------------------------------------------------
// Pool: g[batch[n]] += x[n]
// ---------------------------------------------------------------------------
__global__ __launch_bounds__(256) void pool_kernel(
    const float* __restrict__ x,
    const int*   __restrict__ batch,
    float*       __restrict__ g)
{
    int idx = blockIdx.x * 256 + threadIdx.x;
    int n = idx >> 5;
    if (n >= NODES) return;
    int c = (idx & 31) << 2;
    int b = batch[n];
    const float4 v = *reinterpret_cast<const float4*>(x + (size_t)n * HID + c);
    float* p = g + (size_t)b * HID + c;
    unsafeAtomicAdd(p + 0, v.x);
    unsafeAtomicAdd(p + 1, v.y);
    unsafeAtomicAdd(p + 2, v.z);
    unsafeAtomicAdd(p + 3, v.w);
}

// ---------------------------------------------------------------------------
// C[M x 128] = act( (A (+ Agg)) @ W[128x128] + bias )
// Block: 256 threads, 32 rows per block. Each thread: 4 rows x 4 cols.
// A rows staged in LDS; W streamed via L1/L2 (64 KB, cache-resident).
// ---------------------------------------------------------------------------
template<bool ADD, bool RELU>
__global__ __launch_bounds__(256) void gemm128_kernel(
    const float* __restrict__ A,
    const float* __restrict__ Agg,
    const float* __restrict__ W,      // [128][128] row-major (k, n)
    const float* __restrict__ bias,   // [128]
    float*       __restrict__ C,
    int M)
{
    __shared__ float As[32][HID];
    const int tid  = threadIdx.x;
    const int row0 = blockIdx.x * 32;

    // Stage 32 rows of A (optionally + Agg) into LDS.
    {
        const int r = tid >> 3;            // 0..31
        const int c = (tid & 7) * 16;      // 0,16,...,112
        const int gr = row0 + r;
        float4* ps = reinterpret_cast<float4*>(&As[r][c]);
        if (gr < M) {
            const float4* pa = reinterpret_cast<const float4*>(A + (size_t)gr * HID + c);
            if (ADD) {
                const float4* pg = reinterpret_cast<const float4*>(Agg + (size_t)gr * HID + c);
                #pragma unroll
                for (int j = 0; j < 4; ++j) {
                    float4 a = pa[j], g = pg[j];
                    ps[j] = make_float4(a.x + g.x, a.y + g.y, a.z + g.z, a.w + g.w);
                }
            } else {
                #pragma unroll
                for (int j = 0; j < 4; ++j) ps[j] = pa[j];
            }
        } else {
            #pragma unroll
            for (int j = 0; j < 4; ++j) ps[j] = make_float4(0.f, 0.f, 0.f, 0.f);
        }
    }
    __syncthreads();

    const int tx = tid & 31;   // column group: cols tx*4 .. tx*4+3
    const int ty = tid >> 5;   // 0..7 ; rows ty, ty+8, ty+16, ty+24

    float4 acc[4];
    #pragma unroll
    for (int i = 0; i < 4; ++i) acc[i] = make_float4(0.f, 0.f, 0.f, 0.f);

    #pragma unroll 4
    for (int k = 0; k < HID; ++k) {
        const float4 w = *reinterpret_cast<const float4*>(W + (size_t)k * HID + tx * 4);
        #pragma unroll
        for (int i = 0; i < 4; ++i) {
            const float a = As[ty + 8 * i][k];
            acc[i].x += a * w.x;
            acc[i].y += a * w.y;
            acc[i].z += a * w.z;
            acc[i].w += a * w.w;
        }
    }

    const float4 b4 = *reinterpret_cast<const float4*>(bias + tx * 4);
    #pragma unroll
    for (int i = 0; i < 4; ++i) {
        const int row = row0 + ty + 8 * i;
        if (row < M) {
            float4 o = make_float4(acc[i].x + b4.x, acc[i].y + b4.y,
                                   acc[i].z + b4.z, acc[i].w + b4.w);
            if (RELU) {
                o.x = fmaxf(o.x, 0.f); o.y = fmaxf(o.y, 0.f);
                o.z = fmaxf(o.z, 0.f); o.w = fmaxf(o.w, 0.f);
            }
            *reinterpret_cast<float4*>(C + (size_t)row * HID + tx * 4) = o;
        }
    }
}

// ---------------------------------------------------------------------------
// Final tiny GEMM: out[500 x 10] = gh[500 x 128] @ W2[128 x 10] + b2
// ---------------------------------------------------------------------------
__global__ __launch_bounds__(256) void final_kernel(
    const float* __restrict__ gh,
    const float* __restrict__ w2,
    const float* __restrict__ b2,
    float*       __restrict__ out)
{
    int idx = blockIdx.x * 256 + threadIdx.x;
    int r = idx >> 4;
    int c = idx & 15;
    if (r >= GRAPHS || c >= OUTC) return;
    float acc = b2[c];
    for (int k = 0; k < HID; ++k)
        acc += gh[(size_t)r * HID + k] * w2[(size_t)k * OUTC + c];
    out[(size_t)r * OUTC + c] = acc;
}

// ---------------------------------------------------------------------------
extern "C" void kernel_launch(void* const* d_in, const int* in_sizes, int n_in,
                              void* d_out, int out_size, void* d_ws, size_t ws_size,
                              hipStream_t stream)
{
    const float* x    = (const float*)d_in[0];
    const float* w1   = (const float*)d_in[1];   // [3][128][128]
    const float* b1   = (const float*)d_in[2];   // [3][128]
    const float* w2   = (const float*)d_in[3];   // [3][128][128]
    const float* b2   = (const float*)d_in[4];   // [3][128]
    const float* mw1  = (const float*)d_in[5];   // [128][128]
    const float* mb1  = (const float*)d_in[6];   // [128]
    const float* mw2  = (const float*)d_in[7];   // [128][10]
    const float* mb2  = (const float*)d_in[8];   // [10]
    const int*   ei   = (const int*)d_in[9];     // [2][800000]
    const int*   batch= (const int*)d_in[10];    // [50000]
    float* out = (float*)d_out;

    float* ws   = (float*)d_ws;
    float* xcur = ws;                                   // NODES*HID
    float* agg  = ws + (size_t)NODES * HID;             // NODES*HID
    float* hmid = ws + 2 * (size_t)NODES * HID;         // NODES*HID
    float* g    = ws + 3 * (size_t)NODES * HID;         // GRAPHS*HID
    float* gh   = g + (size_t)GRAPHS * HID;             // GRAPHS*HID

    const int* src = ei;
    const int* dst = ei + EDGES;

    const dim3 blk(256);
    const int scatterBlocks = (EDGES * 32 + 255) / 256;   // 100000
    const int gemmBlocks    = (NODES + 31) / 32;          // 1563
    const int poolBlocks    = (NODES * 32 + 255) / 256;   // 6250

    const float* cur = x;
    for (int l = 0; l < NLAYERS; ++l) {
        hipMemsetAsync(agg, 0, (size_t)NODES * HID * sizeof(float), stream);
        scatter_kernel<<<scatterBlocks, blk, 0, stream>>>(cur, src, dst, agg);
        gemm128_kernel<true, true><<<gemmBlocks, blk, 0, stream>>>(
            cur, agg, w1 + (size_t)l * HID * HID, b1 + (size_t)l * HID, hmid, NODES);
        gemm128_kernel<false, true><<<gemmBlocks, blk, 0, stream>>>(
            hmid, nullptr, w2 + (size_t)l * HID * HID, b2 + (size_t)l * HID, xcur, NODES);
        cur = xcur;
    }

    hipMemsetAsync(g, 0, (size_t)GRAPHS * HID * sizeof(float), stream);
    pool_kernel<<<poolBlocks, blk, 0, stream>>>(cur, batch, g);

    gemm128_kernel<false, true><<<(GRAPHS + 31) / 32, blk, 0, stream>>>(
        g, nullptr, mw1, mb1, gh, GRAPHS);
    final_kernel<<<(GRAPHS * 16 + 255) / 256, blk, 0, stream>>>(gh, mw2, mb2, out);
}

// Round 2
// 701.896 us; speedup vs baseline: 6.2562x; 6.2562x over previous
//
#include <hip/hip_runtime.h>

#define NODES   50000
#define EDGES   800000
#define GRAPHS  500
#define HID     128
#define OUTC    10
#define NLAYERS 3

// ---------------------------------------------------------------------------
// CSR build step 1: in-degree count (int atomics, low contention)
// ---------------------------------------------------------------------------
__global__ __launch_bounds__(256) void degree_kernel(
    const int* __restrict__ dst, int* __restrict__ deg)
{
    int e = blockIdx.x * 256 + threadIdx.x;
    if (e < EDGES) atomicAdd(&deg[dst[e]], 1);
}

// ---------------------------------------------------------------------------
// CSR build step 2: single-block exclusive scan of deg[NODES] -> rowptr[NODES+1]
// Also rewrites deg (=cursor) in place with the exclusive prefix.
// ---------------------------------------------------------------------------
__global__ __launch_bounds__(1024) void scan_kernel(
    int* __restrict__ cursor,   // in: deg counts, out: exclusive prefix
    int* __restrict__ rowptr)
{
    __shared__ int lds[1024];
    const int t = threadIdx.x;
    const int C = (NODES + 1023) / 1024;    // 49
    const int lo = t * C;
    const int hi = min(lo + C, NODES);

    int s = 0;
    for (int i = lo; i < hi; ++i) s += cursor[i];
    lds[t] = s;
    __syncthreads();

    // Hillis-Steele inclusive scan over 1024 partials
    for (int off = 1; off < 1024; off <<= 1) {
        int v = (t >= off) ? lds[t - off] : 0;
        __syncthreads();
        lds[t] += v;
        __syncthreads();
    }

    int pre = (t == 0) ? 0 : lds[t - 1];
    for (int i = lo; i < hi; ++i) {
        int d = cursor[i];          // read BEFORE overwriting (in-place safe)
        rowptr[i] = pre;
        cursor[i] = pre;
        pre += d;
    }
    if (t == 1023) rowptr[NODES] = lds[1023];
}

// ---------------------------------------------------------------------------
// CSR build step 3: bucket-fill incoming-edge source lists
// ---------------------------------------------------------------------------
__global__ __launch_bounds__(256) void fill_kernel(
    const int* __restrict__ src, const int* __restrict__ dst,
    int* __restrict__ cursor, int* __restrict__ csr)
{
    int e = blockIdx.x * 256 + threadIdx.x;
    if (e < EDGES) {
        int pos = atomicAdd(&cursor[dst[e]], 1);
        csr[pos] = src[e];
    }
}

// ---------------------------------------------------------------------------
// Aggregation by gather: hin[n] = x[n] + sum_{s in inN(n)} x[s]
// One wave (64 lanes x float2 = 128 ch) per node. No atomics.
// ---------------------------------------------------------------------------
__global__ __launch_bounds__(256) void gather_kernel(
    const float* __restrict__ x,
    const int*   __restrict__ rowptr,
    const int*   __restrict__ csr,
    float*       __restrict__ hin)
{
    const int w    = threadIdx.x >> 6;
    const int lane = threadIdx.x & 63;
    const int n    = blockIdx.x * 4 + w;
    if (n >= NODES) return;

    const float2* x2 = reinterpret_cast<const float2*>(x);
    float2 acc = x2[(size_t)n * 64 + lane];

    const int lo = rowptr[n];
    const int hi = rowptr[n + 1];
    for (int e = lo; e < hi; ++e) {
        int s = csr[e];
        float2 v = x2[(size_t)s * 64 + lane];
        acc.x += v.x;
        acc.y += v.y;
    }
    reinterpret_cast<float2*>(hin)[(size_t)n * 64 + lane] = acc;
}

// ---------------------------------------------------------------------------
// Pool over sorted batch ids: one block per graph, binary-search node range.
// Fully overwrites g -> no memset, no atomics.
// ---------------------------------------------------------------------------
__device__ __forceinline__ int lbound(const int* __restrict__ a, int v)
{
    int lo = 0, hi = NODES;
    while (lo < hi) {
        int m = (lo + hi) >> 1;
        if (a[m] < v) lo = m + 1; else hi = m;
    }
    return lo;
}

__global__ __launch_bounds__(256) void pool_sorted_kernel(
    const float* __restrict__ x,
    const int*   __restrict__ batch,
    float*       __restrict__ g)
{
    const int gid = blockIdx.x;
    const int beg = lbound(batch, gid);
    const int end = lbound(batch, gid + 1);

    const int c    = threadIdx.x & 127;
    const int half = threadIdx.x >> 7;     // 0/1

    float acc = 0.f;
    for (int r = beg + half; r < end; r += 2)
        acc += x[(size_t)r * HID + c];

    __shared__ float lds[256];
    lds[threadIdx.x] = acc;
    __syncthreads();
    if (threadIdx.x < 128)
        g[(size_t)gid * HID + threadIdx.x] = lds[threadIdx.x] + lds[threadIdx.x + 128];
}

// ---------------------------------------------------------------------------
// C[M x 128] = act( A @ W[128x128] + bias )
// Block: 256 threads, 32 rows per block. Each thread: 4 rows x 4 cols.
// ---------------------------------------------------------------------------
template<bool RELU>
__global__ __launch_bounds__(256) void gemm128_kernel(
    const float* __restrict__ A,
    const float* __restrict__ W,      // [128][128] row-major (k, n)
    const float* __restrict__ bias,   // [128]
    float*       __restrict__ C,
    int M)
{
    __shared__ float As[32][HID];
    const int tid  = threadIdx.x;
    const int row0 = blockIdx.x * 32;

    {
        const int r = tid >> 3;            // 0..31
        const int c = (tid & 7) * 16;      // 0,16,...,112
        const int gr = row0 + r;
        float4* ps = reinterpret_cast<float4*>(&As[r][c]);
        if (gr < M) {
            const float4* pa = reinterpret_cast<const float4*>(A + (size_t)gr * HID + c);
            #pragma unroll
            for (int j = 0; j < 4; ++j) ps[j] = pa[j];
        } else {
            #pragma unroll
            for (int j = 0; j < 4; ++j) ps[j] = make_float4(0.f, 0.f, 0.f, 0.f);
        }
    }
    __syncthreads();

    const int tx = tid & 31;   // column group: cols tx*4 .. tx*4+3
    const int ty = tid >> 5;   // rows ty, ty+8, ty+16, ty+24

    float4 acc[4];
    #pragma unroll
    for (int i = 0; i < 4; ++i) acc[i] = make_float4(0.f, 0.f, 0.f, 0.f);

    #pragma unroll 4
    for (int k = 0; k < HID; ++k) {
        const float4 w = *reinterpret_cast<const float4*>(W + (size_t)k * HID + tx * 4);
        #pragma unroll
        for (int i = 0; i < 4; ++i) {
            const float a = As[ty + 8 * i][k];
            acc[i].x += a * w.x;
            acc[i].y += a * w.y;
            acc[i].z += a * w.z;
            acc[i].w += a * w.w;
        }
    }

    const float4 b4 = *reinterpret_cast<const float4*>(bias + tx * 4);
    #pragma unroll
    for (int i = 0; i < 4; ++i) {
        const int row = row0 + ty + 8 * i;
        if (row < M) {
            float4 o = make_float4(acc[i].x + b4.x, acc[i].y + b4.y,
                                   acc[i].z + b4.z, acc[i].w + b4.w);
            if (RELU) {
                o.x = fmaxf(o.x, 0.f); o.y = fmaxf(o.y, 0.f);
                o.z = fmaxf(o.z, 0.f); o.w = fmaxf(o.w, 0.f);
            }
            *reinterpret_cast<float4*>(C + (size_t)row * HID + tx * 4) = o;
        }
    }
}

// ---------------------------------------------------------------------------
// Final tiny GEMM: out[500 x 10] = gh[500 x 128] @ W2[128 x 10] + b2
// ---------------------------------------------------------------------------
__global__ __launch_bounds__(256) void final_kernel(
    const float* __restrict__ gh,
    const float* __restrict__ w2,
    const float* __restrict__ b2,
    float*       __restrict__ out)
{
    int idx = blockIdx.x * 256 + threadIdx.x;
    int r = idx >> 4;
    int c = idx & 15;
    if (r >= GRAPHS || c >= OUTC) return;
    float acc = b2[c];
    for (int k = 0; k < HID; ++k)
        acc += gh[(size_t)r * HID + k] * w2[(size_t)k * OUTC + c];
    out[(size_t)r * OUTC + c] = acc;
}

// ---------------------------------------------------------------------------
extern "C" void kernel_launch(void* const* d_in, const int* in_sizes, int n_in,
                              void* d_out, int out_size, void* d_ws, size_t ws_size,
                              hipStream_t stream)
{
    const float* x    = (const float*)d_in[0];
    const float* w1   = (const float*)d_in[1];   // [3][128][128]
    const float* b1   = (const float*)d_in[2];   // [3][128]
    const float* w2   = (const float*)d_in[3];   // [3][128][128]
    const float* b2   = (const float*)d_in[4];   // [3][128]
    const float* mw1  = (const float*)d_in[5];   // [128][128]
    const float* mb1  = (const float*)d_in[6];   // [128]
    const float* mw2  = (const float*)d_in[7];   // [128][10]
    const float* mb2  = (const float*)d_in[8];   // [10]
    const int*   ei   = (const int*)d_in[9];     // [2][800000]
    const int*   batch= (const int*)d_in[10];    // [50000]
    float* out = (float*)d_out;

    // workspace layout (floats)
    float* b0f = (float*)d_ws;                         // NODES*HID
    float* b1f = b0f + (size_t)NODES * HID;            // NODES*HID
    float* g   = b1f + (size_t)NODES * HID;            // GRAPHS*HID
    float* gh  = g + (size_t)GRAPHS * HID;             // GRAPHS*HID
    int*   cursor = (int*)(gh + (size_t)GRAPHS * HID); // NODES (deg -> cursor)
    int*   rowptr = cursor + NODES;                    // NODES+1
    int*   csr    = rowptr + NODES + 1;                // EDGES

    const int* src = ei;
    const int* dst = ei + EDGES;

    const dim3 blk(256);
    const int edgeBlocks   = (EDGES + 255) / 256;      // 3125
    const int gatherBlocks = (NODES + 3) / 4;          // 12500
    const int gemmBlocks   = (NODES + 31) / 32;        // 1563

    // ---- CSR build (once per call) ----
    hipMemsetAsync(cursor, 0, (size_t)NODES * sizeof(int), stream);
    degree_kernel<<<edgeBlocks, blk, 0, stream>>>(dst, cursor);
    scan_kernel<<<1, 1024, 0, stream>>>(cursor, rowptr);
    fill_kernel<<<edgeBlocks, blk, 0, stream>>>(src, dst, cursor, csr);

    // ---- 3 GIN layers ----
    const float* cur = x;
    for (int l = 0; l < NLAYERS; ++l) {
        float* A = (l == 0) ? b0f : ((cur == b0f) ? b1f : b0f);  // hin buffer
        float* B = (l == 0) ? b1f : (float*)cur;                  // hmid buffer
        gather_kernel<<<gatherBlocks, blk, 0, stream>>>(cur, rowptr, csr, A);
        gemm128_kernel<true><<<gemmBlocks, blk, 0, stream>>>(
            A, w1 + (size_t)l * HID * HID, b1 + (size_t)l * HID, B, NODES);
        gemm128_kernel<true><<<gemmBlocks, blk, 0, stream>>>(
            B, w2 + (size_t)l * HID * HID, b2 + (size_t)l * HID, A, NODES);
        cur = A;
    }

    // ---- pool + MLP ----
    pool_sorted_kernel<<<GRAPHS, blk, 0, stream>>>(cur, batch, g);
    gemm128_kernel<true><<<(GRAPHS + 31) / 32, blk, 0, stream>>>(
        g, mw1, mb1, gh, GRAPHS);
    final_kernel<<<(GRAPHS * 16 + 255) / 256, blk, 0, stream>>>(gh, mw2, mb2, out);
}

// Round 3
// 529.249 us; speedup vs baseline: 8.2971x; 1.3262x over previous
//
#include <hip/hip_runtime.h>

#define NODES   50000
#define EDGES   800000
#define GRAPHS  500
#define HID     128
#define OUTC    10
#define NLAYERS 3

typedef __bf16 bf16x8 __attribute__((ext_vector_type(8)));
typedef float  f32x4  __attribute__((ext_vector_type(4)));

__device__ __forceinline__ unsigned short f2bf(float f){
    unsigned u = __float_as_uint(f);
    u = (u + 0x7fffu + ((u >> 16) & 1u)) >> 16;
    return (unsigned short)u;
}
__device__ __forceinline__ float bf2f(unsigned short h){
    return __uint_as_float(((unsigned)h) << 16);
}

// ---------------------------------------------------------------------------
// CSR build
// ---------------------------------------------------------------------------
__global__ __launch_bounds__(256) void degree_kernel(
    const int* __restrict__ dst, int* __restrict__ deg)
{
    int e = blockIdx.x * 256 + threadIdx.x;
    if (e < EDGES) atomicAdd(&deg[dst[e]], 1);
}

// per-block sums of deg (196 blocks x 256)
__global__ __launch_bounds__(256) void scan_partial_kernel(
    const int* __restrict__ deg, int* __restrict__ bsum)
{
    __shared__ int s[256];
    int i = blockIdx.x * 256 + threadIdx.x;
    int v = (i < NODES) ? deg[i] : 0;
    s[threadIdx.x] = v;
    __syncthreads();
    for (int off = 128; off > 0; off >>= 1) {
        if (threadIdx.x < off) s[threadIdx.x] += s[threadIdx.x + off];
        __syncthreads();
    }
    if (threadIdx.x == 0) bsum[blockIdx.x] = s[0];
}

// exclusive scan of the 196 block sums (single small block)
__global__ __launch_bounds__(256) void scan_small_kernel(
    const int* __restrict__ bsum, int* __restrict__ boff)
{
    __shared__ int s[256];
    const int t = threadIdx.x;
    const int nb = (NODES + 255) / 256;     // 196
    int v = (t < nb) ? bsum[t] : 0;
    s[t] = v;
    __syncthreads();
    for (int off = 1; off < 256; off <<= 1) {
        int u = (t >= off) ? s[t - off] : 0;
        __syncthreads();
        s[t] += u;
        __syncthreads();
    }
    if (t < nb) boff[t] = s[t] - v;         // exclusive
}

// block-local exclusive scan + block offset -> rowptr & cursor
__global__ __launch_bounds__(256) void scan_final_kernel(
    int* __restrict__ cursor,               // in: deg, out: exclusive prefix
    const int* __restrict__ boff,
    int* __restrict__ rowptr)
{
    __shared__ int s[256];
    const int t = threadIdx.x;
    const int i = blockIdx.x * 256 + t;
    int v = (i < NODES) ? cursor[i] : 0;
    s[t] = v;
    __syncthreads();
    for (int off = 1; off < 256; off <<= 1) {
        int u = (t >= off) ? s[t - off] : 0;
        __syncthreads();
        s[t] += u;
        __syncthreads();
    }
    if (i < NODES) {
        int excl = s[t] - v + boff[blockIdx.x];
        rowptr[i] = excl;
        cursor[i] = excl;
    }
    if (blockIdx.x == 0 && t == 0) rowptr[NODES] = EDGES;
}

__global__ __launch_bounds__(256) void fill_kernel(
    const int* __restrict__ src, const int* __restrict__ dst,
    int* __restrict__ cursor, int* __restrict__ csr)
{
    int e = blockIdx.x * 256 + threadIdx.x;
    if (e < EDGES) {
        int pos = atomicAdd(&cursor[dst[e]], 1);
        csr[pos] = src[e];
    }
}

// ---------------------------------------------------------------------------
// Weight prep: wt[m][n][k] = bf16(w[m][k][n]), m = 0..2 -> w1, 3..5 -> w2
// ---------------------------------------------------------------------------
__global__ __launch_bounds__(256) void prep_w_kernel(
    const float* __restrict__ w1, const float* __restrict__ w2,
    unsigned short* __restrict__ wt)
{
    int idx = blockIdx.x * 256 + threadIdx.x;
    if (idx >= 6 * HID * HID) return;
    int m = idx >> 14;
    int n = (idx >> 7) & 127;
    int k = idx & 127;
    const float* w = (m < 3) ? (w1 + (size_t)m * HID * HID)
                             : (w2 + (size_t)(m - 3) * HID * HID);
    wt[idx] = f2bf(w[(size_t)k * HID + n]);
}

// ---------------------------------------------------------------------------
// Aggregation by gather (one wave per node): hin[n] = x[n] + sum x[neighbors]
// ---------------------------------------------------------------------------
__global__ __launch_bounds__(256) void gather_f32_kernel(
    const float* __restrict__ x,
    const int* __restrict__ rowptr, const int* __restrict__ csr,
    unsigned short* __restrict__ hin)
{
    const int w = threadIdx.x >> 6, lane = threadIdx.x & 63;
    const int n = blockIdx.x * 4 + w;
    if (n >= NODES) return;
    const float2* x2 = reinterpret_cast<const float2*>(x);
    float2 a = x2[(size_t)n * 64 + lane];
    float ax = a.x, ay = a.y;
    const int lo = rowptr[n], hi = rowptr[n + 1];
    for (int e = lo; e < hi; ++e) {
        int s = csr[e];
        float2 v = x2[(size_t)s * 64 + lane];
        ax += v.x; ay += v.y;
    }
    unsigned o = ((unsigned)f2bf(ay) << 16) | f2bf(ax);
    reinterpret_cast<unsigned*>(hin)[(size_t)n * 64 + lane] = o;
}

__global__ __launch_bounds__(256) void gather_bf16_kernel(
    const unsigned short* __restrict__ x,
    const int* __restrict__ rowptr, const int* __restrict__ csr,
    unsigned short* __restrict__ hin)
{
    const int w = threadIdx.x >> 6, lane = threadIdx.x & 63;
    const int n = blockIdx.x * 4 + w;
    if (n >= NODES) return;
    const unsigned* x2 = reinterpret_cast<const unsigned*>(x);
    unsigned a = x2[(size_t)n * 64 + lane];
    float ax = bf2f((unsigned short)(a & 0xffff));
    float ay = bf2f((unsigned short)(a >> 16));
    const int lo = rowptr[n], hi = rowptr[n + 1];
    for (int e = lo; e < hi; ++e) {
        int s = csr[e];
        unsigned v = x2[(size_t)s * 64 + lane];
        ax += bf2f((unsigned short)(v & 0xffff));
        ay += bf2f((unsigned short)(v >> 16));
    }
    unsigned o = ((unsigned)f2bf(ay) << 16) | f2bf(ax);
    reinterpret_cast<unsigned*>(hin)[(size_t)n * 64 + lane] = o;
}

// ---------------------------------------------------------------------------
// MFMA GEMM: C[M x 128] = relu( A[M x 128] @ W + bias ), all bf16 in/out.
// Wt is W^T ([n][k] row-major bf16). Block = 4 waves, 64-row tile.
// Operand-swapped mfma: D[n][m] tiles -> packed 8B stores per lane.
// ---------------------------------------------------------------------------
__global__ __launch_bounds__(256) void gemm_mfma_kernel(
    const unsigned short* __restrict__ A,
    const unsigned short* __restrict__ Wt,
    const float* __restrict__ bias,
    unsigned short* __restrict__ C,
    int M)
{
    __shared__ unsigned short As[64][136];   // +8 pad: 2-way banks = free
    const int tid  = threadIdx.x;
    const int row0 = blockIdx.x * 64;

    #pragma unroll
    for (int j = 0; j < 4; ++j) {
        int chunk = tid + 256 * j;          // 0..1023
        int r  = chunk >> 4;                // 0..63
        int cw = chunk & 15;                // 16B chunk in row
        int gr = row0 + r;
        uint4 v = make_uint4(0u, 0u, 0u, 0u);
        if (gr < M) v = *reinterpret_cast<const uint4*>(A + (size_t)gr * HID + cw * 8);
        *reinterpret_cast<uint4*>(&As[r][cw * 8]) = v;
    }
    __syncthreads();

    const int w    = tid >> 6;
    const int lane = tid & 63;
    const int lr   = lane & 15;
    const int lg   = lane >> 4;

    bf16x8 afrag[4];
    #pragma unroll
    for (int s = 0; s < 4; ++s)
        afrag[s] = *reinterpret_cast<const bf16x8*>(&As[w * 16 + lr][s * 32 + lg * 8]);

    f32x4 acc[8];
    #pragma unroll
    for (int nt = 0; nt < 8; ++nt) acc[nt] = (f32x4){0.f, 0.f, 0.f, 0.f};

    const unsigned short* wp = Wt + (size_t)lr * HID + lg * 8;
    #pragma unroll
    for (int nt = 0; nt < 8; ++nt) {
        const unsigned short* wn = wp + (size_t)nt * 16 * HID;
        #pragma unroll
        for (int s = 0; s < 4; ++s) {
            bf16x8 b = *reinterpret_cast<const bf16x8*>(wn + s * 32);
            acc[nt] = __builtin_amdgcn_mfma_f32_16x16x32_bf16(b, afrag[s], acc[nt], 0, 0, 0);
        }
    }

    const int row = row0 + w * 16 + lr;
    if (row < M) {
        const float4* b4p = reinterpret_cast<const float4*>(bias);
        #pragma unroll
        for (int nt = 0; nt < 8; ++nt) {
            int col = nt * 16 + lg * 4;
            float4 b4 = b4p[nt * 4 + lg];
            ushort4 o;
            o.x = f2bf(fmaxf(acc[nt][0] + b4.x, 0.f));
            o.y = f2bf(fmaxf(acc[nt][1] + b4.y, 0.f));
            o.z = f2bf(fmaxf(acc[nt][2] + b4.z, 0.f));
            o.w = f2bf(fmaxf(acc[nt][3] + b4.w, 0.f));
            *reinterpret_cast<ushort4*>(C + (size_t)row * HID + col) = o;
        }
    }
}

// ---------------------------------------------------------------------------
// Pool over sorted batch ids (bf16 in, f32 out)
// ---------------------------------------------------------------------------
__device__ __forceinline__ int lbound(const int* __restrict__ a, int v)
{
    int lo = 0, hi = NODES;
    while (lo < hi) {
        int m = (lo + hi) >> 1;
        if (a[m] < v) lo = m + 1; else hi = m;
    }
    return lo;
}

__global__ __launch_bounds__(256) void pool_sorted_kernel(
    const unsigned short* __restrict__ x,
    const int* __restrict__ batch,
    float* __restrict__ g)
{
    const int gid = blockIdx.x;
    const int beg = lbound(batch, gid);
    const int end = lbound(batch, gid + 1);

    const int c    = threadIdx.x & 127;
    const int half = threadIdx.x >> 7;

    float acc = 0.f;
    for (int r = beg + half; r < end; r += 2)
        acc += bf2f(x[(size_t)r * HID + c]);

    __shared__ float lds[256];
    lds[threadIdx.x] = acc;
    __syncthreads();
    if (threadIdx.x < 128)
        g[(size_t)gid * HID + threadIdx.x] = lds[threadIdx.x] + lds[threadIdx.x + 128];
}

// ---------------------------------------------------------------------------
// Small f32 GEMM for the graph-level MLP (M=500)
// ---------------------------------------------------------------------------
__global__ __launch_bounds__(256) void gemm128_f32_kernel(
    const float* __restrict__ A,
    const float* __restrict__ W,
    const float* __restrict__ bias,
    float* __restrict__ C,
    int M)
{
    __shared__ float As[32][HID];
    const int tid  = threadIdx.x;
    const int row0 = blockIdx.x * 32;

    {
        const int r = tid >> 3;
        const int c = (tid & 7) * 16;
        const int gr = row0 + r;
        float4* ps = reinterpret_cast<float4*>(&As[r][c]);
        if (gr < M) {
            const float4* pa = reinterpret_cast<const float4*>(A + (size_t)gr * HID + c);
            #pragma unroll
            for (int j = 0; j < 4; ++j) ps[j] = pa[j];
        } else {
            #pragma unroll
            for (int j = 0; j < 4; ++j) ps[j] = make_float4(0.f, 0.f, 0.f, 0.f);
        }
    }
    __syncthreads();

    const int tx = tid & 31;
    const int ty = tid >> 5;

    float4 acc[4];
    #pragma unroll
    for (int i = 0; i < 4; ++i) acc[i] = make_float4(0.f, 0.f, 0.f, 0.f);

    #pragma unroll 4
    for (int k = 0; k < HID; ++k) {
        const float4 w = *reinterpret_cast<const float4*>(W + (size_t)k * HID + tx * 4);
        #pragma unroll
        for (int i = 0; i < 4; ++i) {
            const float a = As[ty + 8 * i][k];
            acc[i].x += a * w.x;
            acc[i].y += a * w.y;
            acc[i].z += a * w.z;
            acc[i].w += a * w.w;
        }
    }

    const float4 b4 = *reinterpret_cast<const float4*>(bias + tx * 4);
    #pragma unroll
    for (int i = 0; i < 4; ++i) {
        const int row = row0 + ty + 8 * i;
        if (row < M) {
            float4 o = make_float4(fmaxf(acc[i].x + b4.x, 0.f),
                                   fmaxf(acc[i].y + b4.y, 0.f),
                                   fmaxf(acc[i].z + b4.z, 0.f),
                                   fmaxf(acc[i].w + b4.w, 0.f));
            *reinterpret_cast<float4*>(C + (size_t)row * HID + tx * 4) = o;
        }
    }
}

__global__ __launch_bounds__(256) void final_kernel(
    const float* __restrict__ gh,
    const float* __restrict__ w2,
    const float* __restrict__ b2,
    float* __restrict__ out)
{
    int idx = blockIdx.x * 256 + threadIdx.x;
    int r = idx >> 4;
    int c = idx & 15;
    if (r >= GRAPHS || c >= OUTC) return;
    float acc = b2[c];
    for (int k = 0; k < HID; ++k)
        acc += gh[(size_t)r * HID + k] * w2[(size_t)k * OUTC + c];
    out[(size_t)r * OUTC + c] = acc;
}

// ---------------------------------------------------------------------------
extern "C" void kernel_launch(void* const* d_in, const int* in_sizes, int n_in,
                              void* d_out, int out_size, void* d_ws, size_t ws_size,
                              hipStream_t stream)
{
    const float* x    = (const float*)d_in[0];
    const float* w1   = (const float*)d_in[1];
    const float* b1   = (const float*)d_in[2];
    const float* w2   = (const float*)d_in[3];
    const float* b2   = (const float*)d_in[4];
    const float* mw1  = (const float*)d_in[5];
    const float* mb1  = (const float*)d_in[6];
    const float* mw2  = (const float*)d_in[7];
    const float* mb2  = (const float*)d_in[8];
    const int*   ei   = (const int*)d_in[9];
    const int*   batch= (const int*)d_in[10];
    float* out = (float*)d_out;

    // workspace layout
    char* p = (char*)d_ws;
    unsigned short* hb0 = (unsigned short*)p;  p += (size_t)NODES * HID * 2;
    unsigned short* hb1 = (unsigned short*)p;  p += (size_t)NODES * HID * 2;
    unsigned short* wt  = (unsigned short*)p;  p += (size_t)6 * HID * HID * 2;
    float* g      = (float*)p;                 p += (size_t)GRAPHS * HID * 4;
    float* gh     = (float*)p;                 p += (size_t)GRAPHS * HID * 4;
    int*   cursor = (int*)p;                   p += (size_t)NODES * 4;
    int*   rowptr = (int*)p;                   p += (size_t)(NODES + 1) * 4;
    int*   csr    = (int*)p;                   p += (size_t)EDGES * 4;
    int*   bsum   = (int*)p;                   p += 256 * 4;
    int*   boff   = (int*)p;

    const int* src = ei;
    const int* dst = ei + EDGES;

    const dim3 blk(256);
    const int edgeBlocks   = (EDGES + 255) / 256;      // 3125
    const int scanBlocks   = (NODES + 255) / 256;      // 196
    const int gatherBlocks = (NODES + 3) / 4;          // 12500
    const int gemmBlocks   = (NODES + 63) / 64;        // 782

    // ---- CSR build ----
    hipMemsetAsync(cursor, 0, (size_t)NODES * sizeof(int), stream);
    degree_kernel<<<edgeBlocks, blk, 0, stream>>>(dst, cursor);
    scan_partial_kernel<<<scanBlocks, blk, 0, stream>>>(cursor, bsum);
    scan_small_kernel<<<1, blk, 0, stream>>>(bsum, boff);
    scan_final_kernel<<<scanBlocks, blk, 0, stream>>>(cursor, boff, rowptr);
    fill_kernel<<<edgeBlocks, blk, 0, stream>>>(src, dst, cursor, csr);
    prep_w_kernel<<<(6 * HID * HID + 255) / 256, blk, 0, stream>>>(w1, w2, wt);

    // ---- 3 GIN layers (ping-pong hb0/hb1) ----
    // L0: gather(x->hb0), gemm(hb0->hb1), gemm(hb1->hb0)
    gather_f32_kernel<<<gatherBlocks, blk, 0, stream>>>(x, rowptr, csr, hb0);
    gemm_mfma_kernel<<<gemmBlocks, blk, 0, stream>>>(hb0, wt + 0 * HID * HID, b1 + 0 * HID, hb1, NODES);
    gemm_mfma_kernel<<<gemmBlocks, blk, 0, stream>>>(hb1, wt + 3 * HID * HID, b2 + 0 * HID, hb0, NODES);
    // L1
    gather_bf16_kernel<<<gatherBlocks, blk, 0, stream>>>(hb0, rowptr, csr, hb1);
    gemm_mfma_kernel<<<gemmBlocks, blk, 0, stream>>>(hb1, wt + 1 * HID * HID, b1 + 1 * HID, hb0, NODES);
    gemm_mfma_kernel<<<gemmBlocks, blk, 0, stream>>>(hb0, wt + 4 * HID * HID, b2 + 1 * HID, hb1, NODES);
    // L2
    gather_bf16_kernel<<<gatherBlocks, blk, 0, stream>>>(hb1, rowptr, csr, hb0);
    gemm_mfma_kernel<<<gemmBlocks, blk, 0, stream>>>(hb0, wt + 2 * HID * HID, b1 + 2 * HID, hb1, NODES);
    gemm_mfma_kernel<<<gemmBlocks, blk, 0, stream>>>(hb1, wt + 5 * HID * HID, b2 + 2 * HID, hb0, NODES);

    // ---- pool + MLP ----
    pool_sorted_kernel<<<GRAPHS, blk, 0, stream>>>(hb0, batch, g);
    gemm128_f32_kernel<<<(GRAPHS + 31) / 32, blk, 0, stream>>>(g, mw1, mb1, gh, GRAPHS);
    final_kernel<<<(GRAPHS * 16 + 255) / 256, blk, 0, stream>>>(gh, mw2, mb2, out);
}

// Round 4
// 388.332 us; speedup vs baseline: 11.3079x; 1.3629x over previous
//
#include <hip/hip_runtime.h>

#define NODES   50000
#define EDGES   800000
#define GRAPHS  500
#define HID     128
#define OUTC    10
#define NLAYERS 3

typedef __bf16 bf16x8 __attribute__((ext_vector_type(8)));
typedef float  f32x4  __attribute__((ext_vector_type(4)));

__device__ __forceinline__ unsigned short f2bf(float f){
    unsigned u = __float_as_uint(f);
    u = (u + 0x7fffu + ((u >> 16) & 1u)) >> 16;
    return (unsigned short)u;
}
__device__ __forceinline__ float bf2f(unsigned short h){
    return __uint_as_float(((unsigned)h) << 16);
}

// ---------------------------------------------------------------------------
// CSR build
// ---------------------------------------------------------------------------
__global__ __launch_bounds__(256) void degree_kernel(
    const int* __restrict__ dst, int* __restrict__ deg)
{
    int e = blockIdx.x * 256 + threadIdx.x;
    if (e < EDGES) atomicAdd(&deg[dst[e]], 1);
}

__global__ __launch_bounds__(256) void scan_partial_kernel(
    const int* __restrict__ deg, int* __restrict__ bsum)
{
    __shared__ int s[256];
    int i = blockIdx.x * 256 + threadIdx.x;
    int v = (i < NODES) ? deg[i] : 0;
    s[threadIdx.x] = v;
    __syncthreads();
    for (int off = 128; off > 0; off >>= 1) {
        if (threadIdx.x < off) s[threadIdx.x] += s[threadIdx.x + off];
        __syncthreads();
    }
    if (threadIdx.x == 0) bsum[blockIdx.x] = s[0];
}

__global__ __launch_bounds__(256) void scan_small_kernel(
    const int* __restrict__ bsum, int* __restrict__ boff)
{
    __shared__ int s[256];
    const int t = threadIdx.x;
    const int nb = (NODES + 255) / 256;     // 196
    int v = (t < nb) ? bsum[t] : 0;
    s[t] = v;
    __syncthreads();
    for (int off = 1; off < 256; off <<= 1) {
        int u = (t >= off) ? s[t - off] : 0;
        __syncthreads();
        s[t] += u;
        __syncthreads();
    }
    if (t < nb) boff[t] = s[t] - v;         // exclusive
}

__global__ __launch_bounds__(256) void scan_final_kernel(
    int* __restrict__ cursor,
    const int* __restrict__ boff,
    int* __restrict__ rowptr)
{
    __shared__ int s[256];
    const int t = threadIdx.x;
    const int i = blockIdx.x * 256 + t;
    int v = (i < NODES) ? cursor[i] : 0;
    s[t] = v;
    __syncthreads();
    for (int off = 1; off < 256; off <<= 1) {
        int u = (t >= off) ? s[t - off] : 0;
        __syncthreads();
        s[t] += u;
        __syncthreads();
    }
    if (i < NODES) {
        int excl = s[t] - v + boff[blockIdx.x];
        rowptr[i] = excl;
        cursor[i] = excl;
    }
    if (blockIdx.x == 0 && t == 0) rowptr[NODES] = EDGES;
}

__global__ __launch_bounds__(256) void fill_kernel(
    const int* __restrict__ src, const int* __restrict__ dst,
    int* __restrict__ cursor, int* __restrict__ csr)
{
    int e = blockIdx.x * 256 + threadIdx.x;
    if (e < EDGES) {
        int pos = atomicAdd(&cursor[dst[e]], 1);
        csr[pos] = src[e];
    }
}

// ---------------------------------------------------------------------------
// Weight prep: wt[m][n][k] = bf16(w[m][k][n]), m = 0..2 -> w1, 3..5 -> w2
// ---------------------------------------------------------------------------
__global__ __launch_bounds__(256) void prep_w_kernel(
    const float* __restrict__ w1, const float* __restrict__ w2,
    unsigned short* __restrict__ wt)
{
    int idx = blockIdx.x * 256 + threadIdx.x;
    if (idx >= 6 * HID * HID) return;
    int m = idx >> 14;
    int n = (idx >> 7) & 127;
    int k = idx & 127;
    const float* w = (m < 3) ? (w1 + (size_t)m * HID * HID)
                             : (w2 + (size_t)(m - 3) * HID * HID);
    wt[idx] = f2bf(w[(size_t)k * HID + n]);
}

// ---------------------------------------------------------------------------
// x f32 -> bf16 (packed pairs)
// ---------------------------------------------------------------------------
__global__ __launch_bounds__(256) void conv_kernel(
    const float* __restrict__ x, unsigned* __restrict__ xb)
{
    int i = blockIdx.x * 256 + threadIdx.x;   // pair index
    if (i >= NODES * 64) return;
    float2 v = reinterpret_cast<const float2*>(x)[i];
    xb[i] = ((unsigned)f2bf(v.y) << 16) | f2bf(v.x);
}

// ---------------------------------------------------------------------------
// Gather, 4 neighbors in flight: one wave per node, quarter-wave per neighbor
// row (16 lanes x dwordx4 = 256 B = full bf16 row). Cross-quarter shfl reduce.
// hin[n] = x[n] + sum_{s in inN(n)} x[s]
// ---------------------------------------------------------------------------
__global__ __launch_bounds__(256) void gather4_kernel(
    const unsigned short* __restrict__ x,
    const int* __restrict__ rowptr, const int* __restrict__ csr,
    unsigned short* __restrict__ hin)
{
    const int w    = threadIdx.x >> 6;
    const int lane = threadIdx.x & 63;
    const int n    = blockIdx.x * 4 + w;
    if (n >= NODES) return;
    const int q  = lane >> 4;      // quarter 0..3 -> neighbor slot
    const int lr = lane & 15;      // 16B chunk within row (channels lr*8..+8)

    const uint4* xr = reinterpret_cast<const uint4*>(x);   // 16 uint4 per row

    float acc[8];
    #pragma unroll
    for (int i = 0; i < 8; ++i) acc[i] = 0.f;

    const int lo = rowptr[n], hi = rowptr[n + 1];
    for (int e0 = lo; e0 < hi; e0 += 4) {
        const int e = e0 + q;
        uint4 v = make_uint4(0u, 0u, 0u, 0u);
        if (e < hi) {
            int s = csr[e];
            v = xr[(size_t)s * 16 + lr];
        }
        const unsigned uu[4] = {v.x, v.y, v.z, v.w};
        #pragma unroll
        for (int j = 0; j < 4; ++j) {
            acc[2 * j]     += __uint_as_float(uu[j] << 16);
            acc[2 * j + 1] += __uint_as_float(uu[j] & 0xffff0000u);
        }
    }

    #pragma unroll
    for (int i = 0; i < 8; ++i) {
        acc[i] += __shfl_xor(acc[i], 16, 64);
        acc[i] += __shfl_xor(acc[i], 32, 64);
    }

    if (q == 0) {
        uint4 self = xr[(size_t)n * 16 + lr];
        const unsigned su[4] = {self.x, self.y, self.z, self.w};
        uint4 o;
        unsigned* ou = &o.x;
        #pragma unroll
        for (int j = 0; j < 4; ++j) {
            float c0 = acc[2 * j]     + __uint_as_float(su[j] << 16);
            float c1 = acc[2 * j + 1] + __uint_as_float(su[j] & 0xffff0000u);
            ou[j] = ((unsigned)f2bf(c1) << 16) | f2bf(c0);
        }
        reinterpret_cast<uint4*>(hin)[(size_t)n * 16 + lr] = o;
    }
}

// ---------------------------------------------------------------------------
// Fused dual MFMA GEMM: C = relu( relu(A@W1+b1) @ W2 + b2 ), bf16 in/out.
// h1 kept in the LDS A-tile (each wave owns its 16 rows -> no extra barrier).
// Wt* are W^T ([n][k] row-major bf16).
// ---------------------------------------------------------------------------
__global__ __launch_bounds__(256) void gemm_dual_kernel(
    const unsigned short* __restrict__ A,
    const unsigned short* __restrict__ Wt1, const float* __restrict__ bias1,
    const unsigned short* __restrict__ Wt2, const float* __restrict__ bias2,
    unsigned short* __restrict__ C,
    int M)
{
    __shared__ unsigned short As[64][136];   // pad 16B: alignment kept, 2-way banks
    const int tid  = threadIdx.x;
    const int row0 = blockIdx.x * 64;

    #pragma unroll
    for (int j = 0; j < 4; ++j) {
        int chunk = tid + 256 * j;          // 0..1023
        int r  = chunk >> 4;
        int cw = chunk & 15;
        int gr = row0 + r;
        uint4 v = make_uint4(0u, 0u, 0u, 0u);
        if (gr < M) v = *reinterpret_cast<const uint4*>(A + (size_t)gr * HID + cw * 8);
        *reinterpret_cast<uint4*>(&As[r][cw * 8]) = v;
    }
    __syncthreads();

    const int w    = tid >> 6;
    const int lane = tid & 63;
    const int lr   = lane & 15;
    const int lg   = lane >> 4;
    const int arow = w * 16 + lr;

    // ---- GEMM 1 ----
    bf16x8 afrag[4];
    #pragma unroll
    for (int s = 0; s < 4; ++s)
        afrag[s] = *reinterpret_cast<const bf16x8*>(&As[arow][s * 32 + lg * 8]);

    f32x4 acc[8];
    #pragma unroll
    for (int nt = 0; nt < 8; ++nt) acc[nt] = (f32x4){0.f, 0.f, 0.f, 0.f};

    {
        const unsigned short* wp = Wt1 + (size_t)lr * HID + lg * 8;
        #pragma unroll
        for (int nt = 0; nt < 8; ++nt) {
            const unsigned short* wn = wp + (size_t)nt * 16 * HID;
            #pragma unroll
            for (int s = 0; s < 4; ++s) {
                bf16x8 b = *reinterpret_cast<const bf16x8*>(wn + s * 32);
                acc[nt] = __builtin_amdgcn_mfma_f32_16x16x32_bf16(b, afrag[s], acc[nt], 0, 0, 0);
            }
        }
    }

    // bias1 + relu -> h1 back into LDS (wave-private rows)
    {
        const float4* b4p = reinterpret_cast<const float4*>(bias1);
        #pragma unroll
        for (int nt = 0; nt < 8; ++nt) {
            float4 b4 = b4p[nt * 4 + lg];
            ushort4 o;
            o.x = f2bf(fmaxf(acc[nt][0] + b4.x, 0.f));
            o.y = f2bf(fmaxf(acc[nt][1] + b4.y, 0.f));
            o.z = f2bf(fmaxf(acc[nt][2] + b4.z, 0.f));
            o.w = f2bf(fmaxf(acc[nt][3] + b4.w, 0.f));
            *reinterpret_cast<ushort4*>(&As[arow][nt * 16 + lg * 4]) = o;
        }
    }

    // ---- GEMM 2 ----
    #pragma unroll
    for (int s = 0; s < 4; ++s)
        afrag[s] = *reinterpret_cast<const bf16x8*>(&As[arow][s * 32 + lg * 8]);

    #pragma unroll
    for (int nt = 0; nt < 8; ++nt) acc[nt] = (f32x4){0.f, 0.f, 0.f, 0.f};

    {
        const unsigned short* wp = Wt2 + (size_t)lr * HID + lg * 8;
        #pragma unroll
        for (int nt = 0; nt < 8; ++nt) {
            const unsigned short* wn = wp + (size_t)nt * 16 * HID;
            #pragma unroll
            for (int s = 0; s < 4; ++s) {
                bf16x8 b = *reinterpret_cast<const bf16x8*>(wn + s * 32);
                acc[nt] = __builtin_amdgcn_mfma_f32_16x16x32_bf16(b, afrag[s], acc[nt], 0, 0, 0);
            }
        }
    }

    const int row = row0 + w * 16 + lr;
    if (row < M) {
        const float4* b4p = reinterpret_cast<const float4*>(bias2);
        #pragma unroll
        for (int nt = 0; nt < 8; ++nt) {
            int col = nt * 16 + lg * 4;
            float4 b4 = b4p[nt * 4 + lg];
            ushort4 o;
            o.x = f2bf(fmaxf(acc[nt][0] + b4.x, 0.f));
            o.y = f2bf(fmaxf(acc[nt][1] + b4.y, 0.f));
            o.z = f2bf(fmaxf(acc[nt][2] + b4.z, 0.f));
            o.w = f2bf(fmaxf(acc[nt][3] + b4.w, 0.f));
            *reinterpret_cast<ushort4*>(C + (size_t)row * HID + col) = o;
        }
    }
}

// ---------------------------------------------------------------------------
// Pool over sorted batch ids (bf16 in, f32 out)
// ---------------------------------------------------------------------------
__device__ __forceinline__ int lbound(const int* __restrict__ a, int v)
{
    int lo = 0, hi = NODES;
    while (lo < hi) {
        int m = (lo + hi) >> 1;
        if (a[m] < v) lo = m + 1; else hi = m;
    }
    return lo;
}

__global__ __launch_bounds__(256) void pool_sorted_kernel(
    const unsigned short* __restrict__ x,
    const int* __restrict__ batch,
    float* __restrict__ g)
{
    const int gid = blockIdx.x;
    const int beg = lbound(batch, gid);
    const int end = lbound(batch, gid + 1);

    const int c    = threadIdx.x & 127;
    const int half = threadIdx.x >> 7;

    float acc = 0.f;
    for (int r = beg + half; r < end; r += 2)
        acc += bf2f(x[(size_t)r * HID + c]);

    __shared__ float lds[256];
    lds[threadIdx.x] = acc;
    __syncthreads();
    if (threadIdx.x < 128)
        g[(size_t)gid * HID + threadIdx.x] = lds[threadIdx.x] + lds[threadIdx.x + 128];
}

// ---------------------------------------------------------------------------
// Small f32 GEMM for the graph-level MLP (M=500)
// ---------------------------------------------------------------------------
__global__ __launch_bounds__(256) void gemm128_f32_kernel(
    const float* __restrict__ A,
    const float* __restrict__ W,
    const float* __restrict__ bias,
    float* __restrict__ C,
    int M)
{
    __shared__ float As[32][HID];
    const int tid  = threadIdx.x;
    const int row0 = blockIdx.x * 32;

    {
        const int r = tid >> 3;
        const int c = (tid & 7) * 16;
        const int gr = row0 + r;
        float4* ps = reinterpret_cast<float4*>(&As[r][c]);
        if (gr < M) {
            const float4* pa = reinterpret_cast<const float4*>(A + (size_t)gr * HID + c);
            #pragma unroll
            for (int j = 0; j < 4; ++j) ps[j] = pa[j];
        } else {
            #pragma unroll
            for (int j = 0; j < 4; ++j) ps[j] = make_float4(0.f, 0.f, 0.f, 0.f);
        }
    }
    __syncthreads();

    const int tx = tid & 31;
    const int ty = tid >> 5;

    float4 acc[4];
    #pragma unroll
    for (int i = 0; i < 4; ++i) acc[i] = make_float4(0.f, 0.f, 0.f, 0.f);

    #pragma unroll 4
    for (int k = 0; k < HID; ++k) {
        const float4 w = *reinterpret_cast<const float4*>(W + (size_t)k * HID + tx * 4);
        #pragma unroll
        for (int i = 0; i < 4; ++i) {
            const float a = As[ty + 8 * i][k];
            acc[i].x += a * w.x;
            acc[i].y += a * w.y;
            acc[i].z += a * w.z;
            acc[i].w += a * w.w;
        }
    }

    const float4 b4 = *reinterpret_cast<const float4*>(bias + tx * 4);
    #pragma unroll
    for (int i = 0; i < 4; ++i) {
        const int row = row0 + ty + 8 * i;
        if (row < M) {
            float4 o = make_float4(fmaxf(acc[i].x + b4.x, 0.f),
                                   fmaxf(acc[i].y + b4.y, 0.f),
                                   fmaxf(acc[i].z + b4.z, 0.f),
                                   fmaxf(acc[i].w + b4.w, 0.f));
            *reinterpret_cast<float4*>(C + (size_t)row * HID + tx * 4) = o;
        }
    }
}

__global__ __launch_bounds__(256) void final_kernel(
    const float* __restrict__ gh,
    const float* __restrict__ w2,
    const float* __restrict__ b2,
    float* __restrict__ out)
{
    int idx = blockIdx.x * 256 + threadIdx.x;
    int r = idx >> 4;
    int c = idx & 15;
    if (r >= GRAPHS || c >= OUTC) return;
    float acc = b2[c];
    for (int k = 0; k < HID; ++k)
        acc += gh[(size_t)r * HID + k] * w2[(size_t)k * OUTC + c];
    out[(size_t)r * OUTC + c] = acc;
}

// ---------------------------------------------------------------------------
extern "C" void kernel_launch(void* const* d_in, const int* in_sizes, int n_in,
                              void* d_out, int out_size, void* d_ws, size_t ws_size,
                              hipStream_t stream)
{
    const float* x    = (const float*)d_in[0];
    const float* w1   = (const float*)d_in[1];
    const float* b1   = (const float*)d_in[2];
    const float* w2   = (const float*)d_in[3];
    const float* b2   = (const float*)d_in[4];
    const float* mw1  = (const float*)d_in[5];
    const float* mb1  = (const float*)d_in[6];
    const float* mw2  = (const float*)d_in[7];
    const float* mb2  = (const float*)d_in[8];
    const int*   ei   = (const int*)d_in[9];
    const int*   batch= (const int*)d_in[10];
    float* out = (float*)d_out;

    // workspace layout
    char* p = (char*)d_ws;
    unsigned short* bufB = (unsigned short*)p;  p += (size_t)NODES * HID * 2; // xb / layer outputs
    unsigned short* t0   = (unsigned short*)p;  p += (size_t)NODES * HID * 2; // gather output
    unsigned short* wt   = (unsigned short*)p;  p += (size_t)6 * HID * HID * 2;
    float* g      = (float*)p;                  p += (size_t)GRAPHS * HID * 4;
    float* gh     = (float*)p;                  p += (size_t)GRAPHS * HID * 4;
    int*   cursor = (int*)p;                    p += (size_t)NODES * 4;
    int*   rowptr = (int*)p;                    p += (size_t)(NODES + 1) * 4;
    int*   csr    = (int*)p;                    p += (size_t)EDGES * 4;
    int*   bsum   = (int*)p;                    p += 256 * 4;
    int*   boff   = (int*)p;

    const int* src = ei;
    const int* dst = ei + EDGES;

    const dim3 blk(256);
    const int edgeBlocks   = (EDGES + 255) / 256;      // 3125
    const int scanBlocks   = (NODES + 255) / 256;      // 196
    const int gatherBlocks = (NODES + 3) / 4;          // 12500
    const int gemmBlocks   = (NODES + 63) / 64;        // 782
    const int convBlocks   = (NODES * 64 + 255) / 256; // 12500

    // ---- CSR build + weight/x prep ----
    hipMemsetAsync(cursor, 0, (size_t)NODES * sizeof(int), stream);
    degree_kernel<<<edgeBlocks, blk, 0, stream>>>(dst, cursor);
    scan_partial_kernel<<<scanBlocks, blk, 0, stream>>>(cursor, bsum);
    scan_small_kernel<<<1, blk, 0, stream>>>(bsum, boff);
    scan_final_kernel<<<scanBlocks, blk, 0, stream>>>(cursor, boff, rowptr);
    fill_kernel<<<edgeBlocks, blk, 0, stream>>>(src, dst, cursor, csr);
    prep_w_kernel<<<(6 * HID * HID + 255) / 256, blk, 0, stream>>>(w1, w2, wt);
    conv_kernel<<<convBlocks, blk, 0, stream>>>(x, (unsigned*)bufB);

    // ---- 3 GIN layers: gather(bufB->t0); dual-gemm(t0->bufB) ----
    for (int l = 0; l < NLAYERS; ++l) {
        gather4_kernel<<<gatherBlocks, blk, 0, stream>>>(bufB, rowptr, csr, t0);
        gemm_dual_kernel<<<gemmBlocks, blk, 0, stream>>>(
            t0,
            wt + (size_t)l * HID * HID,       b1 + (size_t)l * HID,
            wt + (size_t)(l + 3) * HID * HID, b2 + (size_t)l * HID,
            bufB, NODES);
    }

    // ---- pool + MLP ----
    pool_sorted_kernel<<<GRAPHS, blk, 0, stream>>>(bufB, batch, g);
    gemm128_f32_kernel<<<(GRAPHS + 31) / 32, blk, 0, stream>>>(g, mw1, mb1, gh, GRAPHS);
    final_kernel<<<(GRAPHS * 16 + 255) / 256, blk, 0, stream>>>(gh, mw2, mb2, out);
}